// Round 1
// baseline (280.475 us; speedup 1.0000x reference)
//
#include <hip/hip_runtime.h>
#include <hip/hip_bf16.h>

// MultiHeadAttention: B=2, S=2048, H=1024, NH=16, DK=64
// Pipeline: x->bf16 | W^T bf16 | QKV GEMM (bf16 MFMA) | V->V^T | flash attn
//           (alibi+mask, online softmax) | out GEMM (f32 out).
// All GEMM/attn tiles staged via global_load_lds (16B) with XOR-8 slot swizzle
// (rows of 64 bf16 = 128B = 8x16B slots; slot ^= row&7) to avoid the 16-way
// ds_read_b128 bank conflict on 128B-stride row-major tiles.

#define S_LEN 2048
#define H_DIM 1024
#define N_HEADS 16

typedef __bf16 bf16x8 __attribute__((ext_vector_type(8)));
typedef float f32x4 __attribute__((ext_vector_type(4)));

using gvoid = __attribute__((address_space(1))) void;
using svoid = __attribute__((address_space(3))) void;

static __device__ __forceinline__ f32x4 mfma16(bf16x8 a, bf16x8 b, f32x4 c) {
  return __builtin_amdgcn_mfma_f32_16x16x32_bf16(a, b, c, 0, 0, 0);
}

// Stage a [ROWS][64] bf16 tile into LDS via global_load_lds, 16B per lane.
// LDS layout: linear rows of 128B, 16B slot s holds global slot s^(r&7).
// NCH = ROWS/8 * ... = total 1KB wave-chunks = ROWS*128B/1024 = ROWS/8.
template <int NCH>
static __device__ __forceinline__ void stage64(const __bf16* g, int rstride,
                                               __bf16* lds, int wid, int lane) {
#pragma unroll
  for (int i = 0; i < NCH / 4; ++i) {
    int chunk = i * 4 + wid;
    int u = chunk * 64 + lane;
    int r = u >> 3, s = u & 7;
    const __bf16* src = g + (size_t)r * rstride + ((s ^ (r & 7)) << 3);
    __builtin_amdgcn_global_load_lds((const gvoid*)src,
                                     (svoid*)(lds + chunk * 512), 16, 0, 0);
  }
}

// Read an 8-elem fragment at (row r, k-slot "slot") from a swizzled [.][64] tile.
static __device__ __forceinline__ bf16x8 read_frag(const __bf16* lds, int r,
                                                   int slot) {
  return *(const bf16x8*)(lds + r * 64 + ((slot ^ (r & 7)) << 3));
}

static __device__ __forceinline__ ushort f2bfbits(float f) {
  unsigned u = __float_as_uint(f);
  return (ushort)((u + 0x7FFF + ((u >> 16) & 1)) >> 16);
}

// ---------------------------------------------------------------- convert x
__global__ __launch_bounds__(256) void k_convert_x(const float* __restrict__ x,
                                                   __bf16* __restrict__ xb) {
  size_t idx = ((size_t)blockIdx.x * 256 + threadIdx.x) * 8;
  float4 a = *(const float4*)(x + idx);
  float4 b = *(const float4*)(x + idx + 4);
  bf16x8 o;
  o[0] = (__bf16)a.x; o[1] = (__bf16)a.y; o[2] = (__bf16)a.z; o[3] = (__bf16)a.w;
  o[4] = (__bf16)b.x; o[5] = (__bf16)b.y; o[6] = (__bf16)b.z; o[7] = (__bf16)b.w;
  *(bf16x8*)(xb + idx) = o;
}

// ------------------------------------------------- W [K][N] -> W^T [N][K] bf16
__global__ __launch_bounds__(256) void k_transpose_w(
    const float* __restrict__ w0, const float* __restrict__ w1,
    const float* __restrict__ w2, const float* __restrict__ w3,
    __bf16* __restrict__ wt) {
  __shared__ float t[64][65];
  int z = blockIdx.z;
  const float* W = (z == 0) ? w0 : (z == 1) ? w1 : (z == 2) ? w2 : w3;
  __bf16* O = wt + (size_t)z * H_DIM * H_DIM;
  int k0 = blockIdx.x * 64, n0 = blockIdx.y * 64;
  int tid = threadIdx.x;
  {
    int r = tid >> 4, c4 = tid & 15;
#pragma unroll
    for (int i = 0; i < 4; ++i) {
      float4 v = *(const float4*)(W + (size_t)(k0 + r + i * 16) * H_DIM + n0 + c4 * 4);
      t[r + i * 16][c4 * 4 + 0] = v.x;
      t[r + i * 16][c4 * 4 + 1] = v.y;
      t[r + i * 16][c4 * 4 + 2] = v.z;
      t[r + i * 16][c4 * 4 + 3] = v.w;
    }
  }
  __syncthreads();
  {
    int nn = tid >> 2, js = (tid & 3) * 16;
    bf16x8 o0, o1;
#pragma unroll
    for (int j = 0; j < 8; ++j) {
      o0[j] = (__bf16)t[js + j][nn];
      o1[j] = (__bf16)t[js + 8 + j][nn];
    }
    __bf16* dst = O + (size_t)(n0 + nn) * H_DIM + k0 + js;
    *(bf16x8*)dst = o0;
    *(bf16x8*)(dst + 8) = o1;
  }
}

// --------------------------------- V [bh][s][64] -> VT [bh][64][s]  (bf16)
__global__ __launch_bounds__(256) void k_transpose_v(const __bf16* __restrict__ V,
                                                     __bf16* __restrict__ VT) {
  __shared__ __bf16 t[64][65];
  int bh = blockIdx.y;
  int s0 = blockIdx.x * 64;
  const __bf16* Vb = V + (size_t)bh * S_LEN * 64;
  int tid = threadIdx.x;
#pragma unroll
  for (int i = 0; i < 2; ++i) {
    int u = i * 256 + tid;
    int r = u >> 3, c8 = u & 7;
    bf16x8 v = *(const bf16x8*)(Vb + (size_t)(s0 + r) * 64 + c8 * 8);
#pragma unroll
    for (int j = 0; j < 8; ++j) t[r][c8 * 8 + j] = v[j];
  }
  __syncthreads();
  int d = tid >> 2, js = (tid & 3) * 16;
  bf16x8 o0, o1;
#pragma unroll
  for (int j = 0; j < 8; ++j) {
    o0[j] = t[js + j][d];
    o1[j] = t[js + 8 + j][d];
  }
  __bf16* dst = VT + (size_t)bh * 64 * S_LEN + (size_t)d * S_LEN + s0 + js;
  *(bf16x8*)dst = o0;
  *(bf16x8*)(dst + 8) = o1;
}

// ----------------------------------------------------------------- GEMMs
// MODE 0: C[m][n] = xb[m][:] . Wt[n][:] + bias -> bf16 into [b,h,s,d] (z picks q/k/v)
// MODE 1: C[m][n] = ctx(m as b,q; k as h,d) . Wt_o[n][:] + bias -> f32 out
template <int MODE>
__global__ __launch_bounds__(256) void k_gemm(
    const __bf16* __restrict__ A, const __bf16* __restrict__ B0,
    const __bf16* __restrict__ B1, const __bf16* __restrict__ B2,
    const float* __restrict__ bias0, const float* __restrict__ bias1,
    const float* __restrict__ bias2, __bf16* __restrict__ O0,
    __bf16* __restrict__ O1, __bf16* __restrict__ O2, float* __restrict__ Of) {
  __shared__ alignas(16) __bf16 As[128 * 64];
  __shared__ alignas(16) __bf16 Bs[128 * 64];
  int tid = threadIdx.x, wid = tid >> 6, lane = tid & 63;
  int l15 = lane & 15, lg = lane >> 4;
  int nbase = blockIdx.x * 128, mbase = blockIdx.y * 128;
  const __bf16* Bm;
  const float* bias;
  __bf16* Ob;
  if (MODE == 0) {
    int z = blockIdx.z;
    Bm = (z == 0) ? B0 : (z == 1) ? B1 : B2;
    bias = (z == 0) ? bias0 : (z == 1) ? bias1 : bias2;
    Ob = (z == 0) ? O0 : (z == 1) ? O1 : O2;
  } else {
    Bm = B0; bias = bias0; Ob = O0;
  }
  int wrow = wid >> 1, wcol = wid & 1;
  f32x4 zero = {0.f, 0.f, 0.f, 0.f};
  f32x4 acc[4][4];
#pragma unroll
  for (int i = 0; i < 4; ++i)
#pragma unroll
    for (int j = 0; j < 4; ++j) acc[i][j] = zero;

  for (int kb = 0; kb < H_DIM; kb += 64) {
    __syncthreads();
    const __bf16* Abase;
    int arstride;
    if (MODE == 0) {
      Abase = A + (size_t)mbase * H_DIM + kb;
      arstride = H_DIM;
    } else {
      int b = mbase >> 11, q0 = mbase & 2047, head = kb >> 6;
      Abase = A + ((size_t)(b * N_HEADS + head) * S_LEN + q0) * 64;
      arstride = 64;
    }
    stage64<16>(Abase, arstride, As, wid, lane);
    stage64<16>(Bm + (size_t)nbase * H_DIM + kb, H_DIM, Bs, wid, lane);
    __syncthreads();
#pragma unroll
    for (int t = 0; t < 2; ++t) {
      bf16x8 a[4], bfr[4];
#pragma unroll
      for (int i = 0; i < 4; ++i)
        a[i] = read_frag(As, wrow * 64 + i * 16 + l15, t * 4 + lg);
#pragma unroll
      for (int j = 0; j < 4; ++j)
        bfr[j] = read_frag(Bs, wcol * 64 + j * 16 + l15, t * 4 + lg);
#pragma unroll
      for (int i = 0; i < 4; ++i)
#pragma unroll
        for (int j = 0; j < 4; ++j) acc[i][j] = mfma16(a[i], bfr[j], acc[i][j]);
    }
  }
  float bv[4];
#pragma unroll
  for (int j = 0; j < 4; ++j) bv[j] = bias[nbase + wcol * 64 + j * 16 + l15];
#pragma unroll
  for (int i = 0; i < 4; ++i)
#pragma unroll
    for (int j = 0; j < 4; ++j)
#pragma unroll
      for (int r = 0; r < 4; ++r) {
        int m = mbase + wrow * 64 + i * 16 + lg * 4 + r;
        int col = nbase + wcol * 64 + j * 16 + l15;
        float v = acc[i][j][r] + bv[j];
        if (MODE == 0) {
          size_t off =
              (((size_t)(m >> 11) * N_HEADS + (col >> 6)) * S_LEN + (m & 2047)) * 64 +
              (col & 63);
          Ob[off] = (__bf16)v;
        } else {
          Of[(size_t)m * H_DIM + col] = v;
        }
      }
}

// ------------------------------------------------------------- attention
// grid: (B*NH, S/64); block 256 (4 waves). Wave w owns q rows [w*16, w*16+16).
__global__ __launch_bounds__(256) void k_attn(
    const __bf16* __restrict__ Q, const __bf16* __restrict__ K,
    const __bf16* __restrict__ VT, const float* __restrict__ alibi,
    const int* __restrict__ mask, __bf16* __restrict__ ctx) {
  __shared__ alignas(16) __bf16 Ks[64 * 64];
  __shared__ alignas(16) __bf16 Vs[64 * 64];
  __shared__ alignas(16) __bf16 Ps[4][16 * 72];  // per-wave, +8 pad per row
  int tid = threadIdx.x, wid = tid >> 6, lane = tid & 63;
  int l15 = lane & 15, lg = lane >> 4;
  int bh = blockIdx.x;
  int b = bh & 1, h = bh >> 1;  // b fastest: adjacent blocks share alibi slice
  int qbase = blockIdx.y * 64;
  size_t bho = (size_t)(b * N_HEADS + h);
  const __bf16* Qb = Q + bho * S_LEN * 64;
  const __bf16* Kb = K + bho * S_LEN * 64;
  const __bf16* Vb = VT + bho * 64 * S_LEN;

  // Q fragments straight from global (row-major [q][64], 16B aligned)
  bf16x8 qa[2];
  {
    const __bf16* qrow = Qb + (size_t)(qbase + wid * 16 + l15) * 64;
    qa[0] = *(const bf16x8*)(qrow + lg * 8);
    qa[1] = *(const bf16x8*)(qrow + 32 + lg * 8);
  }
  float mrun[4], lrun[4];
  f32x4 cacc[4];
  f32x4 zero = {0.f, 0.f, 0.f, 0.f};
#pragma unroll
  for (int r = 0; r < 4; ++r) {
    mrun[r] = -__builtin_inff();
    lrun[r] = 0.f;
    cacc[r] = zero;
  }
  const float* abase[4];
  const int* mbase_[4];
#pragma unroll
  for (int r = 0; r < 4; ++r) {
    int q = qbase + wid * 16 + lg * 4 + r;
    abase[r] = alibi + ((size_t)h * S_LEN + q) * S_LEN + l15;
    mbase_[r] = mask + ((size_t)b * S_LEN + q) * S_LEN + l15;
  }

  for (int kt = 0; kt < S_LEN; kt += 64) {
    __syncthreads();
    stage64<8>(Kb + (size_t)kt * 64, 64, Ks, wid, lane);
    stage64<8>(Vb + kt, S_LEN, Vs, wid, lane);
    __syncthreads();

    float alb[4][4];
    int msk[4][4];
#pragma unroll
    for (int r = 0; r < 4; ++r)
#pragma unroll
      for (int c = 0; c < 4; ++c) {
        alb[r][c] = abase[r][kt + c * 16];
        msk[r][c] = mbase_[r][kt + c * 16];
      }

    f32x4 sacc[4];
#pragma unroll
    for (int c = 0; c < 4; ++c) sacc[c] = zero;
#pragma unroll
    for (int t = 0; t < 2; ++t) {
      bf16x8 kf[4];
#pragma unroll
      for (int c = 0; c < 4; ++c) kf[c] = read_frag(Ks, c * 16 + l15, t * 4 + lg);
#pragma unroll
      for (int c = 0; c < 4; ++c) sacc[c] = mfma16(qa[t], kf[c], sacc[c]);
    }

    // online softmax: rows r (q = ..+lg*4+r), cols c*16+l15 across the 16-lane group
    float p[4][4], tmax[4];
#pragma unroll
    for (int r = 0; r < 4; ++r) {
      tmax[r] = -__builtin_inff();
#pragma unroll
      for (int c = 0; c < 4; ++c) {
        float s = msk[r][c] ? sacc[c][r] * 0.125f + alb[r][c] : -1e9f;
        p[r][c] = s;
        tmax[r] = fmaxf(tmax[r], s);
      }
#pragma unroll
      for (int xm = 1; xm < 16; xm <<= 1)
        tmax[r] = fmaxf(tmax[r], __shfl_xor(tmax[r], xm));
    }
    float scl[4];
#pragma unroll
    for (int r = 0; r < 4; ++r) {
      float mn = fmaxf(mrun[r], tmax[r]);
      scl[r] = __expf(mrun[r] - mn);
      mrun[r] = mn;
      float rs = 0.f;
#pragma unroll
      for (int c = 0; c < 4; ++c) {
        float pe = __expf(p[r][c] - mn);
        p[r][c] = pe;
        rs += pe;
      }
#pragma unroll
      for (int xm = 1; xm < 16; xm <<= 1) rs += __shfl_xor(rs, xm);
      lrun[r] = lrun[r] * scl[r] + rs;
    }
#pragma unroll
    for (int c = 0; c < 4; ++c) {
      f32x4 v = cacc[c];
      v[0] *= scl[0]; v[1] *= scl[1]; v[2] *= scl[2]; v[3] *= scl[3];
      cacc[c] = v;
    }
    // P -> per-wave LDS (row q_local, col kpos_local), padded stride 72
#pragma unroll
    for (int r = 0; r < 4; ++r)
#pragma unroll
      for (int c = 0; c < 4; ++c)
        Ps[wid][(lg * 4 + r) * 72 + c * 16 + l15] = (__bf16)p[r][c];
    // PV
#pragma unroll
    for (int t = 0; t < 2; ++t) {
      bf16x8 pa = *(const bf16x8*)(&Ps[wid][l15 * 72 + t * 32 + lg * 8]);
#pragma unroll
      for (int c = 0; c < 4; ++c) {
        bf16x8 vb = read_frag(Vs, c * 16 + l15, t * 4 + lg);
        cacc[c] = mfma16(pa, vb, cacc[c]);
      }
    }
  }
  // epilogue: ctx[b,h,q,d] bf16
#pragma unroll
  for (int c = 0; c < 4; ++c)
#pragma unroll
    for (int r = 0; r < 4; ++r) {
      int q = qbase + wid * 16 + lg * 4 + r;
      int d = c * 16 + l15;
      ctx[bho * S_LEN * 64 + (size_t)q * 64 + d] = (__bf16)(cacc[c][r] / lrun[r]);
    }
}

// ----------------------------------------------------------------- launch
extern "C" void kernel_launch(void* const* d_in, const int* in_sizes, int n_in,
                              void* d_out, int out_size, void* d_ws,
                              size_t ws_size, hipStream_t stream) {
  const float* x = (const float*)d_in[0];
  const int* mask = (const int*)d_in[1];
  const float* alibi = (const float*)d_in[2];
  const float* Wq = (const float*)d_in[3];
  const float* bq = (const float*)d_in[4];
  const float* Wk = (const float*)d_in[5];
  const float* bk = (const float*)d_in[6];
  const float* Wv = (const float*)d_in[7];
  const float* bv = (const float*)d_in[8];
  const float* Wo = (const float*)d_in[9];
  const float* bo = (const float*)d_in[10];
  float* out = (float*)d_out;
  char* ws = (char*)d_ws;

  const size_t MB = 1u << 20;
  __bf16* xb = (__bf16*)(ws);                 // 8MB (reused as ctx later)
  __bf16* wt = (__bf16*)(ws + 8 * MB);        // 8MB: Wq^T,Wk^T,Wv^T,Wo^T
  __bf16* Qb = (__bf16*)(ws + 16 * MB);       // 8MB
  __bf16* Kb = (__bf16*)(ws + 24 * MB);       // 8MB
  __bf16* Vb = (__bf16*)(ws + 32 * MB);       // 8MB
  __bf16* VTb = (__bf16*)(ws + 40 * MB);      // 8MB
  __bf16* ctxb = xb;                          // alias: xb dead after QKV GEMM
  __bf16* wtq = wt;
  __bf16* wtk = wt + (1u << 20);
  __bf16* wtv = wt + 2 * (1u << 20);
  __bf16* wto = wt + 3 * (1u << 20);

  k_convert_x<<<dim3(2048), 256, 0, stream>>>(x, xb);
  k_transpose_w<<<dim3(16, 16, 4), 256, 0, stream>>>(Wq, Wk, Wv, Wo, wt);
  k_gemm<0><<<dim3(8, 32, 3), 256, 0, stream>>>(xb, wtq, wtk, wtv, bq, bk, bv,
                                                Qb, Kb, Vb, nullptr);
  k_transpose_v<<<dim3(32, 32), 256, 0, stream>>>(Vb, VTb);
  k_attn<<<dim3(32, 32), 256, 0, stream>>>(Qb, Kb, VTb, alibi, mask, ctxb);
  k_gemm<1><<<dim3(8, 32, 1), 256, 0, stream>>>(ctxb, wto, nullptr, nullptr, bo,
                                                nullptr, nullptr, nullptr,
                                                nullptr, nullptr, out);
}